// Round 20
// baseline (661.149 us; speedup 1.0000x reference)
//
#include <hip/hip_runtime.h>
#include <hip/hip_fp16.h>
#include <math.h>

#define N_NODES   100000
#define N_EDGES   1600000
#define N_GRAPHS  512
#define FEAT      128
#define EXTRA     8

#define NB    196        // buckets of 512 nodes
#define CAPB  10240      // strided bucket capacity (mean 8163, +23 sigma)
#define PA_T  3072       // edges staged per block in pass A
#define PA_K  12         // PA_T / 256

#define NCH   8          // feature chunks
#define CHW   16         // feats per chunk; slice = N_NODES*CHW*2B = 3.2MB < 4MB L2

typedef _Float16 half8_t __attribute__((ext_vector_type(8)));
typedef float    f32x4_t __attribute__((ext_vector_type(4)));

static __device__ __forceinline__ float selu_f(float x){
    const float alpha = 1.6732632423543772f;
    const float scale = 1.0507009873554805f;
    return scale * (x > 0.0f ? x : alpha * expm1f(x));
}

// init strided bucket cursors
__global__ void k_initcur(int* __restrict__ gcursor, int* __restrict__ scursor){
    int i = threadIdx.x;
    if (i < NB){ gcursor[i] = i*CAPB; scursor[i] = i*CAPB; }
}

// one pass over edges: dst-partition packed (dst&511)|(src<<9) into tmp AND
// src-partition src-low-bits into tmp2, both LDS-staged (coalesced writes)
__global__ __launch_bounds__(256) void k_passA2(
        const int* __restrict__ esrc, const int* __restrict__ edst,
        int* __restrict__ gcursor, int* __restrict__ scursor,
        unsigned* __restrict__ tmp, ushort* __restrict__ tmp2){
    __shared__ int      lcount[NB];
    __shared__ int      lscan[256];
    __shared__ int      gbase[NB];
    __shared__ ushort   bid[PA_T];
    __shared__ unsigned staged[PA_T];
    __shared__ int      Vtot;
    int t = threadIdx.x;
    int base = blockIdx.x * PA_T;

    unsigned ed[PA_K], es[PA_K]; int valid[PA_K];
    #pragma unroll
    for (int k = 0; k < PA_K; ++k){
        int e = base + k*256 + t;
        valid[k] = (e < N_EDGES);
        ed[k] = valid[k] ? (unsigned)edst[e] : 0u;
        es[k] = valid[k] ? (unsigned)esrc[e] : 0u;
    }

    // ---- phase 1: dst partition ----
    for (int i = t; i < NB; i += 256) lcount[i] = 0;
    __syncthreads();
    int bk[PA_K], slot[PA_K];
    #pragma unroll
    for (int k = 0; k < PA_K; ++k){
        if (valid[k]){
            bk[k] = (int)(ed[k] >> 9);
            slot[k] = atomicAdd(&lcount[bk[k]], 1);
        } else bk[k] = -1;
    }
    __syncthreads();
    int v = (t < NB) ? lcount[t] : 0;
    lscan[t] = v;
    __syncthreads();
    for (int d = 1; d < 256; d <<= 1){
        int u = (t >= d) ? lscan[t-d] : 0;
        __syncthreads();
        lscan[t] += u;
        __syncthreads();
    }
    int excl = lscan[t] - v;
    if (t < NB) gbase[t] = atomicAdd(&gcursor[t], v);
    __syncthreads();
    lscan[t] = excl;
    if (t == 255) Vtot = excl + v;
    __syncthreads();
    #pragma unroll
    for (int k = 0; k < PA_K; ++k){
        if (bk[k] >= 0){
            int i = lscan[bk[k]] + slot[k];
            staged[i] = (ed[k] & 511u) | (es[k] << 9);
            bid[i] = (ushort)bk[k];
        }
    }
    __syncthreads();
    {
        int total = Vtot;
        for (int i = t; i < total; i += 256){
            int b = bid[i];
            tmp[gbase[b] + (i - lscan[b])] = staged[i];
        }
    }
    __syncthreads();

    // ---- phase 2: src partition ----
    ushort* sstag = (ushort*)staged;
    for (int i = t; i < NB; i += 256) lcount[i] = 0;
    __syncthreads();
    #pragma unroll
    for (int k = 0; k < PA_K; ++k){
        if (valid[k]){
            bk[k] = (int)(es[k] >> 9);
            slot[k] = atomicAdd(&lcount[bk[k]], 1);
        } else bk[k] = -1;
    }
    __syncthreads();
    v = (t < NB) ? lcount[t] : 0;
    lscan[t] = v;
    __syncthreads();
    for (int d = 1; d < 256; d <<= 1){
        int u = (t >= d) ? lscan[t-d] : 0;
        __syncthreads();
        lscan[t] += u;
        __syncthreads();
    }
    excl = lscan[t] - v;
    if (t < NB) gbase[t] = atomicAdd(&scursor[t], v);
    __syncthreads();
    lscan[t] = excl;
    if (t == 255) Vtot = excl + v;
    __syncthreads();
    #pragma unroll
    for (int k = 0; k < PA_K; ++k){
        if (bk[k] >= 0){
            int i = lscan[bk[k]] + slot[k];
            sstag[i] = (ushort)(es[k] & 511u);
            bid[i] = (ushort)bk[k];
        }
    }
    __syncthreads();
    {
        int total = Vtot;
        for (int i = t; i < total; i += 256){
            int b = bid[i];
            tmp2[gbase[b] + (i - lscan[b])] = sstag[i];
        }
    }
}

// per src-bucket LDS histogram -> ns (strided buckets)
__global__ __launch_bounds__(256) void k_srchist(
        const ushort* __restrict__ tmp2, const int* __restrict__ scursor,
        float* __restrict__ ns){
    __shared__ int hc[512];
    int b = blockIdx.x, t = threadIdx.x;
    int node0 = b << 9;
    int lo = b*CAPB;
    int hi = scursor[b]; if (hi > lo + CAPB) hi = lo + CAPB;
    hc[t] = 0; hc[t+256] = 0;
    __syncthreads();
    for (int p = lo + t; p < hi; p += 256)
        atomicAdd(&hc[tmp2[p]], 1);
    __syncthreads();
    int n0 = node0 + t, n1 = n0 + 256;
    if (n0 < N_NODES){ int c = hc[t];     ns[n0] = rsqrtf((float)(c > 1 ? c : 1)); }
    if (n1 < N_NODES){ int c = hc[t+256]; ns[n1] = rsqrtf((float)(c > 1 ? c : 1)); }
}

// pass B: one block per dst bucket -> row_beg/row_end, nd, col (strided buckets)
// col stores CHUNK-ROW byte offsets: src * CHW * 2 = src << 5
__global__ __launch_bounds__(256) void k_passB(
        const unsigned* __restrict__ tmp, const int* __restrict__ gcursor,
        int* __restrict__ row_beg, int* __restrict__ row_end,
        int* __restrict__ col, float* __restrict__ nd){
    __shared__ int hc[512];
    __shared__ int hs[512];
    int b = blockIdx.x, t = threadIdx.x;
    int node0 = b << 9;
    int lo = b*CAPB;
    int hi = gcursor[b]; if (hi > lo + CAPB) hi = lo + CAPB;
    hc[t] = 0; hc[t+256] = 0;
    __syncthreads();
    for (int p = lo + t; p < hi; p += 256)
        atomicAdd(&hc[tmp[p] & 511u], 1);
    __syncthreads();
    int a0 = hc[2*t], a1 = hc[2*t+1];
    int s = a0 + a1;
    hs[t] = s;
    __syncthreads();
    for (int d = 1; d < 256; d <<= 1){
        int u = (t >= d) ? hs[t-d] : 0;
        __syncthreads();
        hs[t] += u;
        __syncthreads();
    }
    int excl = hs[t] - s;
    __syncthreads();
    hs[2*t]   = excl;
    hs[2*t+1] = excl + a0;
    int n0 = node0 + 2*t, n1 = n0 + 1;
    if (n0 < N_NODES){
        row_beg[n0] = lo + excl;
        row_end[n0] = lo + excl + a0;
        nd[n0] = rsqrtf((float)(a0 > 1 ? a0 : 1));
    }
    if (n1 < N_NODES){
        row_beg[n1] = lo + excl + a0;
        row_end[n1] = lo + excl + a0 + a1;
        nd[n1] = rsqrtf((float)(a1 > 1 ? a1 : 1));
    }
    __syncthreads();
    for (int p = lo + t; p < hi; p += 256){
        unsigned e = tmp[p];
        int slot = atomicAdd(&hs[e & 511u], 1);
        col[lo + slot] = (int)((e >> 9) << 5);   // chunk-row byte offset
    }
}

// prep: xc[c][node][16 feats] = fp16( x * ns ), chunk-major, coalesced writes
__global__ void k_prep(const float2* __restrict__ x2, const float* __restrict__ ns,
                       __half2* __restrict__ xc2){
    int c = blockIdx.y;
    int i = blockIdx.x*blockDim.x + threadIdx.x;   // [0, N_NODES*8)
    if (i < N_NODES*8){
        int node = i >> 3;
        int dw   = i & 7;
        float w = ns[node];
        float2 v = x2[(size_t)node*64 + c*8 + dw];
        xc2[(size_t)c*N_NODES*8 + i] = __floats2half2_rn(v.x*w, v.y*w);
    }
}

// swizzle TWO 128x128 fp32 weights into MFMA-fragment order, fp16 (one launch)
__global__ void k_wprep2(const float* __restrict__ W1, __half* __restrict__ Wf1,
                         const float* __restrict__ W2, __half* __restrict__ Wf2){
    int gi = blockIdx.x*256 + threadIdx.x;
    const float* W  = (gi < 16384) ? W1 : W2;
    __half* Wf      = (gi < 16384) ? Wf1 : Wf2;
    int i = gi & 16383;
    int j = i & 7, lane = (i>>3) & 63, kk = (i>>9) & 3, c = i>>11;
    int k = kk*32 + ((lane>>4)<<3) + j;
    int cc = (c<<4) + (lane & 15);
    Wf[i] = __float2half(W[k*FEAT + cc]);
}

// CHUNKED aggregate: blockIdx&7 = feature chunk -> XCD-affine (round-robin
// dispatch pins chunk c to XCD c; its 3.2MB slice is L2-resident).
// 256 thr = 4 waves = 4 nodes; wave = 8 edge-slots x 8 feat-lanes x 4B.
__global__ __launch_bounds__(256) void k_aggregate_c(
        const __half* __restrict__ xc, const int* __restrict__ row_beg,
        const int* __restrict__ row_end, const int* __restrict__ col,
        const float* __restrict__ nd, __half* __restrict__ outc){
    int chunk = blockIdx.x & 7;
    int node  = (blockIdx.x >> 3)*4 + (threadIdx.x >> 6);
    int lane = threadIdx.x & 63;
    int es = lane >> 3, f = lane & 7;
    const char* base = (const char*)(xc + (size_t)chunk*N_NODES*CHW) + f*4;
    int beg = row_beg[node], end = row_end[node];

    __half2 acc = __floats2half2_rn(0.f, 0.f);
    for (int eb = beg; eb < end; eb += 32){
        int off[4]; unsigned r[4];
        #pragma unroll
        for (int j = 0; j < 4; ++j){
            int e = eb + 8*j + es;
            off[j] = (e < end) ? col[e] : -1;
        }
        #pragma unroll
        for (int j = 0; j < 4; ++j)
            r[j] = (off[j] >= 0) ? *(const unsigned*)(base + off[j]) : 0u;
        #pragma unroll
        for (int j = 0; j < 4; ++j){
            union { unsigned u; __half2 h; } cv; cv.u = r[j];
            acc = __hadd2(acc, cv.h);
        }
    }
    // reduce across the 8 edge-slots
    #pragma unroll
    for (int m = 8; m < 64; m <<= 1){
        union { __half2 h; int i; } u, v;
        u.h = acc;
        v.i = __shfl_xor(u.i, m, 64);
        acc = __hadd2(u.h, v.h);
    }
    if (lane < 8){
        float wd = nd[node];
        float2 fv = __half22float2(acc);
        union { __half2 h; unsigned u; } pk;
        pk.h = __floats2half2_rn(fv.x*wd, fv.y*wd);
        *(unsigned*)((char*)outc + (size_t)chunk*N_NODES*32 + (size_t)node*32 + f*4) = pk.u;
    }
}

// MFMA GEMM: 64 rows/block (4 waves x 16 rows); A and output CHUNK-MAJOR.
// hout = fp16(selu(acc+b)*ns)
__global__ __launch_bounds__(256) void k_gemm_mfma(
        const __half* __restrict__ A, const __half* __restrict__ Wf,
        const float* __restrict__ bias, const float* __restrict__ ns,
        __half* __restrict__ hout){
    int w = threadIdx.x >> 6, lane = threadIdx.x & 63;
    int r0 = blockIdx.x*64 + w*16;
    int rl = lane & 15, kg = lane >> 4;
    int arow = r0 + rl;

    half8_t a[4];
    if (arow < N_NODES){
        #pragma unroll
        for (int kk = 0; kk < 4; ++kk){
            int feat0 = kg*8 + kk*32;
            int ci = feat0 >> 4, inner = feat0 & 15;
            a[kk] = *(const half8_t*)(A + (size_t)ci*N_NODES*CHW + (size_t)arow*CHW + inner);
        }
    } else {
        #pragma unroll
        for (int kk = 0; kk < 4; ++kk) a[kk] = (half8_t)(_Float16)0;
    }

    const half8_t* Bf = (const half8_t*)Wf;
    f32x4_t acc[8];
    #pragma unroll
    for (int c = 0; c < 8; ++c){
        acc[c] = (f32x4_t){0.f,0.f,0.f,0.f};
        #pragma unroll
        for (int kk = 0; kk < 4; ++kk){
            half8_t b = Bf[(c*4 + kk)*64 + lane];
            acc[c] = __builtin_amdgcn_mfma_f32_16x16x32_f16(a[kk], b, acc[c], 0, 0, 0);
        }
    }

    int orow0 = r0 + kg*4;
    float nsv[4];
    #pragma unroll
    for (int r = 0; r < 4; ++r)
        nsv[r] = (orow0 + r < N_NODES) ? ns[orow0 + r] : 0.f;
    #pragma unroll
    for (int c = 0; c < 8; ++c){
        float bv = bias[c*16 + rl];
        #pragma unroll
        for (int r = 0; r < 4; ++r){
            int orow = orow0 + r;
            if (orow < N_NODES){
                float v = acc[c][r] + bv;
                v = selu_f(v);
                // chunk-major: chunk=c, inner=rl
                hout[(size_t)c*N_NODES*CHW + (size_t)orow*CHW + rl] = __float2half(v * nsv[r]);
            }
        }
    }
}

__global__ void k_goff(const int* __restrict__ gid, int* __restrict__ goff){
    int g = blockIdx.x*blockDim.x + threadIdx.x;
    if (g > N_GRAPHS) return;
    if (g == N_GRAPHS){ goff[g] = N_NODES; return; }
    int lo = 0, hi = N_NODES;
    while (lo < hi){
        int mid = (lo + hi) >> 1;
        if (gid[mid] < g) lo = mid + 1; else hi = mid;
    }
    goff[g] = lo;
}

// readout on CHUNK-MAJOR fp16 aggregate: 4 chunk-blocks per graph
__global__ __launch_bounds__(256) void k_readout_h(
        const __half* __restrict__ ah, const int* __restrict__ goff,
        float* __restrict__ emb_part){
    __shared__ float red[16][FEAT];
    int g = blockIdx.x >> 2, c = blockIdx.x & 3;
    int t = threadIdx.x;
    int fl = t & 15, rs = t >> 4;
    int ci = fl >> 1, inner = (fl & 1)*8;
    const __half* basep = ah + (size_t)ci*N_NODES*CHW + inner;
    int beg = goff[g], end = goff[g+1];
    int cnt = end - beg;
    int chunk = (cnt + 3) >> 2;
    int lo = beg + c*chunk;
    int hi = lo + chunk; if (hi > end) hi = end;
    float acc[8] = {0,0,0,0,0,0,0,0};
    for (int r = lo + rs; r < hi; r += 16){
        uint4 v = *(const uint4*)(basep + (size_t)r*CHW);
        const __half2* h = (const __half2*)&v;
        #pragma unroll
        for (int q = 0; q < 4; ++q){
            float2 f = __half22float2(h[q]);
            acc[2*q]   += f.x;
            acc[2*q+1] += f.y;
        }
    }
    #pragma unroll
    for (int q = 0; q < 8; ++q) red[rs][fl*8+q] = acc[q];
    __syncthreads();
    if (t < FEAT){
        float s = 0.f;
        #pragma unroll
        for (int i = 0; i < 16; ++i) s += red[i][t];
        emb_part[((size_t)g*4 + c)*FEAT + t] = s;
    }
}

// block per graph: mean(parts) -> @W3+b3 -> concat fg -> 136->256->128->1 MLP
__global__ __launch_bounds__(256) void k_mlp(
        const float* __restrict__ emb_part, const int* __restrict__ goff,
        const float* __restrict__ fg,
        const float* __restrict__ W3, const float* __restrict__ b3,
        const float* __restrict__ Wl1, const float* __restrict__ bl1,
        const float* __restrict__ Wl2, const float* __restrict__ bl2,
        const float* __restrict__ Wl3, const float* __restrict__ bl3,
        float* __restrict__ out){
    __shared__ float e[FEAT];
    __shared__ float in136[FEAT+EXTRA];
    __shared__ float y1[256];
    __shared__ float y2[128];
    int g = blockIdx.x, t = threadIdx.x;
    int cnt = goff[g+1] - goff[g]; if (cnt < 1) cnt = 1;
    float inv = 1.f / (float)cnt;
    if (t < FEAT){
        const float* p = emb_part + (size_t)g*4*FEAT;
        e[t] = (p[t] + p[FEAT+t] + p[2*FEAT+t] + p[3*FEAT+t]) * inv;
    }
    __syncthreads();
    if (t < FEAT){
        float acc = b3[t];
        for (int i = 0; i < FEAT; ++i) acc += e[i] * W3[i*FEAT + t];
        in136[t] = acc;
    } else if (t < FEAT+EXTRA){
        in136[t] = fg[g*EXTRA + (t-FEAT)];
    }
    __syncthreads();
    {
        float acc = bl1[t];
        for (int i = 0; i < FEAT+EXTRA; ++i) acc += in136[i] * Wl1[i*256 + t];
        y1[t] = selu_f(acc);
    }
    __syncthreads();
    if (t < 128){
        float acc = bl2[t];
        for (int i = 0; i < 256; ++i) acc += y1[i] * Wl2[i*128 + t];
        y2[t] = selu_f(acc);
    }
    __syncthreads();
    if (t == 0){
        float s = bl3[0];
        for (int i = 0; i < 128; ++i) s += y2[i] * Wl3[i];
        out[g] = s;
    }
}

extern "C" void kernel_launch(void* const* d_in, const int* in_sizes, int n_in,
                              void* d_out, int out_size, void* d_ws, size_t ws_size,
                              hipStream_t stream){
    const float* feats_node  = (const float*)d_in[0];
    const float* feats_graph = (const float*)d_in[1];
    const int*   edge_src    = (const int*)d_in[2];
    const int*   edge_dst    = (const int*)d_in[3];
    const int*   graph_ids   = (const int*)d_in[4];
    const float* W1 =(const float*)d_in[5];  const float* b1 =(const float*)d_in[6];
    const float* W2 =(const float*)d_in[7];  const float* b2 =(const float*)d_in[8];
    const float* W3 =(const float*)d_in[9];  const float* b3 =(const float*)d_in[10];
    const float* Wl1=(const float*)d_in[11]; const float* bl1=(const float*)d_in[12];
    const float* Wl2=(const float*)d_in[13]; const float* bl2=(const float*)d_in[14];
    const float* Wl3=(const float*)d_in[15]; const float* bl3=(const float*)d_in[16];
    float* out = (float*)d_out;
    (void)in_sizes; (void)n_in; (void)out_size; (void)ws_size;

    char* ws = (char*)d_ws;
    size_t off = 0;
    auto alloc = [&](size_t bytes)->void*{
        void* p = ws + off;
        off += (bytes + 255) & ~(size_t)255;
        return p;
    };
    __half*   xh      = (__half*)  alloc((size_t)N_NODES*FEAT*2);  // chunk-major
    __half*   ah      = (__half*)  alloc((size_t)N_NODES*FEAT*2);  // chunk-major
    float*    ns      = (float*)   alloc((size_t)N_NODES*4);
    float*    nd      = (float*)   alloc((size_t)N_NODES*4);
    int*      row_beg = (int*)     alloc((size_t)N_NODES*4);
    int*      row_end = (int*)     alloc((size_t)N_NODES*4);
    int*      col     = (int*)     alloc((size_t)NB*CAPB*4);
    unsigned* tmp     = (unsigned*)alloc((size_t)NB*CAPB*4);
    ushort*   tmp2    = (ushort*)  alloc((size_t)NB*CAPB*2);
    int*      gcursor = (int*)     alloc((size_t)NB*4);
    int*      scursor = (int*)     alloc((size_t)NB*4);
    __half*   Wf1     = (__half*)  alloc((size_t)16384*2);
    __half*   Wf2     = (__half*)  alloc((size_t)16384*2);
    int*      goff    = (int*)     alloc((size_t)(N_GRAPHS+1)*4);
    float*    emb_part= (float*)   alloc((size_t)N_GRAPHS*4*FEAT*4);

    // strided-bucket CSR build (packed payload; col = chunk-row byte offsets)
    k_initcur<<<dim3(1), dim3(256), 0, stream>>>(gcursor, scursor);
    k_passA2<<<dim3((N_EDGES + PA_T - 1)/PA_T), dim3(256), 0, stream>>>(
        edge_src, edge_dst, gcursor, scursor, tmp, tmp2);
    k_passB<<<dim3(NB), dim3(256), 0, stream>>>(tmp, gcursor, row_beg, row_end, col, nd);
    k_srchist<<<dim3(NB), dim3(256), 0, stream>>>(tmp2, scursor, ns);

    // weight fragment swizzle (fp16)
    k_wprep2<<<dim3(128), dim3(256), 0, stream>>>(W1, Wf1, W2, Wf2);

    // fp16 pre-scaled input, chunk-major
    k_prep<<<dim3((N_NODES*8 + 255)/256, NCH), dim3(256), 0, stream>>>(
        (const float2*)feats_node, ns, (__half2*)xh);

    // graph offsets
    k_goff<<<dim3((N_GRAPHS+1+255)/256), dim3(256), 0, stream>>>(graph_ids, goff);

    // 3 GraphConv layers, split kernels; chunked XCD-affine aggregate
    dim3 aggGrid(NCH * (N_NODES/4));           // 200000, chunk = blockIdx & 7
    dim3 gemmGrid((N_NODES + 63)/64);
    k_aggregate_c<<<aggGrid, dim3(256), 0, stream>>>(xh, row_beg, row_end, col, nd, ah);
    k_gemm_mfma<<<gemmGrid, dim3(256), 0, stream>>>(ah, Wf1, b1, ns, xh);
    k_aggregate_c<<<aggGrid, dim3(256), 0, stream>>>(xh, row_beg, row_end, col, nd, ah);
    k_gemm_mfma<<<gemmGrid, dim3(256), 0, stream>>>(ah, Wf2, b2, ns, xh);
    k_aggregate_c<<<aggGrid, dim3(256), 0, stream>>>(xh, row_beg, row_end, col, nd, ah);

    // readout + fused (mean @ W3 + b3) inside MLP
    k_readout_h<<<dim3(N_GRAPHS*4), dim3(256), 0, stream>>>(ah, goff, emb_part);
    k_mlp<<<dim3(N_GRAPHS), dim3(256), 0, stream>>>(emb_part, goff, feats_graph,
        W3, b3, Wl1, bl1, Wl2, bl2, Wl3, bl3, out);
}

// Round 21
// 322.995 us; speedup vs baseline: 2.0469x; 2.0469x over previous
//
#include <hip/hip_runtime.h>
#include <hip/hip_fp16.h>
#include <math.h>

#define N_NODES   100000
#define N_EDGES   1600000
#define N_GRAPHS  512
#define FEAT      128
#define EXTRA     8

#define NB    196        // buckets of 512 nodes
#define CAPB  10240      // strided bucket capacity (mean 8163, +23 sigma)
#define PA_T  3072       // edges staged per block in pass A
#define PA_K  12         // PA_T / 256

typedef _Float16 half8_t __attribute__((ext_vector_type(8)));
typedef float    f32x4_t __attribute__((ext_vector_type(4)));

static __device__ __forceinline__ float selu_f(float x){
    const float alpha = 1.6732632423543772f;
    const float scale = 1.0507009873554805f;
    return scale * (x > 0.0f ? x : alpha * expm1f(x));
}

// init strided bucket cursors
__global__ void k_initcur(int* __restrict__ gcursor, int* __restrict__ scursor){
    int i = threadIdx.x;
    if (i < NB){ gcursor[i] = i*CAPB; scursor[i] = i*CAPB; }
}

// one pass over edges: dst-partition packed (dst&511)|(src<<9) into tmp AND
// src-partition src-low-bits into tmp2, both LDS-staged (coalesced writes)
__global__ __launch_bounds__(256) void k_passA2(
        const int* __restrict__ esrc, const int* __restrict__ edst,
        int* __restrict__ gcursor, int* __restrict__ scursor,
        unsigned* __restrict__ tmp, ushort* __restrict__ tmp2){
    __shared__ int      lcount[NB];
    __shared__ int      lscan[256];
    __shared__ int      gbase[NB];
    __shared__ ushort   bid[PA_T];
    __shared__ unsigned staged[PA_T];
    __shared__ int      Vtot;
    int t = threadIdx.x;
    int base = blockIdx.x * PA_T;

    // load edges once
    unsigned ed[PA_K], es[PA_K]; int valid[PA_K];
    #pragma unroll
    for (int k = 0; k < PA_K; ++k){
        int e = base + k*256 + t;
        valid[k] = (e < N_EDGES);
        ed[k] = valid[k] ? (unsigned)edst[e] : 0u;
        es[k] = valid[k] ? (unsigned)esrc[e] : 0u;
    }

    // ---- phase 1: dst partition (payload packed 26 bits) ----
    for (int i = t; i < NB; i += 256) lcount[i] = 0;
    __syncthreads();
    int bk[PA_K], slot[PA_K];
    #pragma unroll
    for (int k = 0; k < PA_K; ++k){
        if (valid[k]){
            bk[k] = (int)(ed[k] >> 9);
            slot[k] = atomicAdd(&lcount[bk[k]], 1);
        } else bk[k] = -1;
    }
    __syncthreads();
    int v = (t < NB) ? lcount[t] : 0;
    lscan[t] = v;
    __syncthreads();
    for (int d = 1; d < 256; d <<= 1){
        int u = (t >= d) ? lscan[t-d] : 0;
        __syncthreads();
        lscan[t] += u;
        __syncthreads();
    }
    int excl = lscan[t] - v;
    if (t < NB) gbase[t] = atomicAdd(&gcursor[t], v);
    __syncthreads();
    lscan[t] = excl;
    if (t == 255) Vtot = excl + v;
    __syncthreads();
    #pragma unroll
    for (int k = 0; k < PA_K; ++k){
        if (bk[k] >= 0){
            int i = lscan[bk[k]] + slot[k];
            staged[i] = (ed[k] & 511u) | (es[k] << 9);
            bid[i] = (ushort)bk[k];
        }
    }
    __syncthreads();
    {
        int total = Vtot;
        for (int i = t; i < total; i += 256){
            int b = bid[i];
            tmp[gbase[b] + (i - lscan[b])] = staged[i];
        }
    }
    __syncthreads();

    // ---- phase 2: src partition (reuse LDS; staged aliased as ushort) ----
    ushort* sstag = (ushort*)staged;
    for (int i = t; i < NB; i += 256) lcount[i] = 0;
    __syncthreads();
    #pragma unroll
    for (int k = 0; k < PA_K; ++k){
        if (valid[k]){
            bk[k] = (int)(es[k] >> 9);
            slot[k] = atomicAdd(&lcount[bk[k]], 1);
        } else bk[k] = -1;
    }
    __syncthreads();
    v = (t < NB) ? lcount[t] : 0;
    lscan[t] = v;
    __syncthreads();
    for (int d = 1; d < 256; d <<= 1){
        int u = (t >= d) ? lscan[t-d] : 0;
        __syncthreads();
        lscan[t] += u;
        __syncthreads();
    }
    excl = lscan[t] - v;
    if (t < NB) gbase[t] = atomicAdd(&scursor[t], v);
    __syncthreads();
    lscan[t] = excl;
    if (t == 255) Vtot = excl + v;
    __syncthreads();
    #pragma unroll
    for (int k = 0; k < PA_K; ++k){
        if (bk[k] >= 0){
            int i = lscan[bk[k]] + slot[k];
            sstag[i] = (ushort)(es[k] & 511u);
            bid[i] = (ushort)bk[k];
        }
    }
    __syncthreads();
    {
        int total = Vtot;
        for (int i = t; i < total; i += 256){
            int b = bid[i];
            tmp2[gbase[b] + (i - lscan[b])] = sstag[i];
        }
    }
}

// per src-bucket LDS histogram -> ns (strided buckets)
__global__ __launch_bounds__(256) void k_srchist(
        const ushort* __restrict__ tmp2, const int* __restrict__ scursor,
        float* __restrict__ ns){
    __shared__ int hc[512];
    int b = blockIdx.x, t = threadIdx.x;
    int node0 = b << 9;
    int lo = b*CAPB;
    int hi = scursor[b]; if (hi > lo + CAPB) hi = lo + CAPB;
    hc[t] = 0; hc[t+256] = 0;
    __syncthreads();
    for (int p = lo + t; p < hi; p += 256)
        atomicAdd(&hc[tmp2[p]], 1);
    __syncthreads();
    int n0 = node0 + t, n1 = n0 + 256;
    if (n0 < N_NODES){ int c = hc[t];     ns[n0] = rsqrtf((float)(c > 1 ? c : 1)); }
    if (n1 < N_NODES){ int c = hc[t+256]; ns[n1] = rsqrtf((float)(c > 1 ? c : 1)); }
}

// pass B: one block per dst bucket -> row_beg/row_end, nd, col (strided buckets)
// tmp packed: (dst&511)|(src<<9). col stores BYTE offsets (src*256).
// row_end EXPLICIT: bucket gaps never read (round-11 lesson).
__global__ __launch_bounds__(256) void k_passB(
        const unsigned* __restrict__ tmp, const int* __restrict__ gcursor,
        int* __restrict__ row_beg, int* __restrict__ row_end,
        int* __restrict__ col, float* __restrict__ nd){
    __shared__ int hc[512];
    __shared__ int hs[512];
    int b = blockIdx.x, t = threadIdx.x;
    int node0 = b << 9;
    int lo = b*CAPB;
    int hi = gcursor[b]; if (hi > lo + CAPB) hi = lo + CAPB;
    hc[t] = 0; hc[t+256] = 0;
    __syncthreads();
    for (int p = lo + t; p < hi; p += 256)
        atomicAdd(&hc[tmp[p] & 511u], 1);
    __syncthreads();
    int a0 = hc[2*t], a1 = hc[2*t+1];
    int s = a0 + a1;
    hs[t] = s;
    __syncthreads();
    for (int d = 1; d < 256; d <<= 1){
        int u = (t >= d) ? hs[t-d] : 0;
        __syncthreads();
        hs[t] += u;
        __syncthreads();
    }
    int excl = hs[t] - s;
    __syncthreads();
    hs[2*t]   = excl;
    hs[2*t+1] = excl + a0;
    int n0 = node0 + 2*t, n1 = n0 + 1;
    if (n0 < N_NODES){
        row_beg[n0] = lo + excl;
        row_end[n0] = lo + excl + a0;
        nd[n0] = rsqrtf((float)(a0 > 1 ? a0 : 1));
    }
    if (n1 < N_NODES){
        row_beg[n1] = lo + excl + a0;
        row_end[n1] = lo + excl + a0 + a1;
        nd[n1] = rsqrtf((float)(a1 > 1 ? a1 : 1));
    }
    __syncthreads();
    for (int p = lo + t; p < hi; p += 256){
        unsigned e = tmp[p];
        int slot = atomicAdd(&hs[e & 511u], 1);
        col[lo + slot] = (int)((e >> 9) << 8);   // byte offset: src * FEAT * 2
    }
}

// xh[i] = fp16( x[i] * ns[node] )
__global__ void k_prep(const float2* __restrict__ x2, const float* __restrict__ ns,
                       __half2* __restrict__ xh2){
    int i = blockIdx.x*blockDim.x + threadIdx.x;
    if (i < N_NODES*64){
        int node = i >> 6;
        float w = ns[node];
        float2 v = x2[i];
        xh2[i] = __floats2half2_rn(v.x*w, v.y*w);
    }
}

// swizzle TWO 128x128 fp32 weights into MFMA-fragment order, fp16 (one launch)
__global__ void k_wprep2(const float* __restrict__ W1, __half* __restrict__ Wf1,
                         const float* __restrict__ W2, __half* __restrict__ Wf2){
    int gi = blockIdx.x*256 + threadIdx.x;
    const float* W  = (gi < 16384) ? W1 : W2;
    __half* Wf      = (gi < 16384) ? Wf1 : Wf2;
    int i = gi & 16383;
    int j = i & 7, lane = (i>>3) & 63, kk = (i>>9) & 3, c = i>>11;
    int k = kk*32 + ((lane>>4)<<3) + j;
    int cc = (c<<4) + (lane & 15);
    Wf[i] = __float2half(W[k*FEAT + cc]);
}

// FUSED aggregate + MFMA GEMM: block = 1024 thr = 16 waves = 16 nodes,
// ONE WAVE PER NODE (R10 lesson); natural node order (R14/16 lesson).
// Phase 1: each wave aggregates its node into a padded LDS row.
// Phase 2: 8 waves do the 16x128 MFMA GEMM + selu*ns epilogue.
__global__ __launch_bounds__(1024, 8) void k_agg_gemm(
        const __half* __restrict__ xh_in, const int* __restrict__ row_beg,
        const int* __restrict__ row_end, const int* __restrict__ col,
        const float* __restrict__ nd, const __half* __restrict__ Wf,
        const float* __restrict__ bias, const float* __restrict__ ns,
        __half* __restrict__ xh_out){
    __shared__ __half Xl[16][136];
    int w = threadIdx.x >> 6, lane = threadIdx.x & 63;
    int sub = lane >> 4, fl = lane & 15;
    int nb0 = blockIdx.x * 16;            // grid exact: 100000 = 6250*16
    int node = nb0 + w;
    {
        int beg = row_beg[node], end = row_end[node];
        const char* base = (const char*)xh_in + fl*16;
        __half2 acc[4];
        #pragma unroll
        for (int q = 0; q < 4; ++q) acc[q] = __floats2half2_rn(0.f, 0.f);
        for (int eb = beg; eb < end; eb += 16){
            int off[4];
            uint4 r[4];
            #pragma unroll
            for (int j = 0; j < 4; ++j){
                int e = eb + 4*j + sub;
                off[j] = (e < end) ? col[e] : -1;
            }
            #pragma unroll
            for (int j = 0; j < 4; ++j){
                r[j] = (off[j] >= 0)
                     ? *(const uint4*)(base + off[j])
                     : make_uint4(0u,0u,0u,0u);
            }
            #pragma unroll
            for (int j = 0; j < 4; ++j){
                const __half2* h = (const __half2*)&r[j];
                #pragma unroll
                for (int q = 0; q < 4; ++q)
                    acc[q] = __hadd2(acc[q], h[q]);
            }
        }
        #pragma unroll
        for (int q = 0; q < 4; ++q){
            union { __half2 h; int i; } u2, v2;
            u2.h = acc[q];
            v2.i = __shfl_xor(u2.i, 16, 64);
            u2.h = __hadd2(u2.h, v2.h);
            v2.i = __shfl_xor(u2.i, 32, 64);
            acc[q] = __hadd2(u2.h, v2.h);
        }
        if (lane < 16){
            float wd = nd[node];
            union { __half2 h[4]; uint4 u; } pk;
            #pragma unroll
            for (int q = 0; q < 4; ++q){
                float2 f = __half22float2(acc[q]);
                pk.h[q] = __floats2half2_rn(f.x*wd, f.y*wd);
            }
            *(uint4*)&Xl[w][fl*8] = pk.u;
        }
    }
    __syncthreads();
    if (w < 8){
        int rl = lane & 15, kg = lane >> 4;
        half8_t a[4];
        #pragma unroll
        for (int kk = 0; kk < 4; ++kk)
            a[kk] = *(const half8_t*)&Xl[rl][kg*8 + kk*32];
        const half8_t* Bf = (const half8_t*)Wf;
        f32x4_t acc = (f32x4_t){0.f,0.f,0.f,0.f};
        #pragma unroll
        for (int kk = 0; kk < 4; ++kk)
            acc = __builtin_amdgcn_mfma_f32_16x16x32_f16(a[kk], Bf[(w*4+kk)*64+lane], acc, 0, 0, 0);
        // C/D: col = lane&15, row = (lane>>4)*4 + reg  [m89-verified]
        int orow0 = nb0 + kg*4;
        int ccol = w*16 + rl;
        float bv = bias[ccol];
        #pragma unroll
        for (int r = 0; r < 4; ++r){
            int orow = orow0 + r;
            float v = acc[r] + bv;
            v = selu_f(v);
            xh_out[(size_t)orow*FEAT + ccol] = __float2half(v * ns[orow]);
        }
    }
}

// layer-3 aggregate (no GEMM): one wave per node, fp16 out (nd folded)
__global__ __launch_bounds__(256) void k_aggregate_h(
        const __half* __restrict__ xh, const int* __restrict__ row_beg,
        const int* __restrict__ row_end, const int* __restrict__ col,
        const float* __restrict__ nd, __half* __restrict__ outh){
    int gid  = blockIdx.x*blockDim.x + threadIdx.x;
    int node = gid >> 6;
    if (node >= N_NODES) return;
    int lane = threadIdx.x & 63;
    int sub  = lane >> 4;
    int fl   = lane & 15;
    int beg = row_beg[node], end = row_end[node];
    const char* base = (const char*)xh + fl*16;

    __half2 acc[4];
    #pragma unroll
    for (int q = 0; q < 4; ++q) acc[q] = __floats2half2_rn(0.f, 0.f);

    for (int eb = beg; eb < end; eb += 16){
        int off[4];
        uint4 r[4];
        #pragma unroll
        for (int j = 0; j < 4; ++j){
            int e = eb + 4*j + sub;
            off[j] = (e < end) ? col[e] : -1;
        }
        #pragma unroll
        for (int j = 0; j < 4; ++j){
            r[j] = (off[j] >= 0)
                 ? *(const uint4*)(base + off[j])
                 : make_uint4(0u,0u,0u,0u);
        }
        #pragma unroll
        for (int j = 0; j < 4; ++j){
            const __half2* h = (const __half2*)&r[j];
            #pragma unroll
            for (int q = 0; q < 4; ++q)
                acc[q] = __hadd2(acc[q], h[q]);
        }
    }
    #pragma unroll
    for (int q = 0; q < 4; ++q){
        union { __half2 h; int i; } u, v;
        u.h = acc[q];
        v.i = __shfl_xor(u.i, 16, 64);
        u.h = __hadd2(u.h, v.h);
        v.i = __shfl_xor(u.i, 32, 64);
        acc[q] = __hadd2(u.h, v.h);
    }
    if (lane < 16){
        float wd = nd[node];
        union { __half2 h[4]; uint4 u; } pk;
        #pragma unroll
        for (int q = 0; q < 4; ++q){
            float2 f = __half22float2(acc[q]);
            pk.h[q] = __floats2half2_rn(f.x*wd, f.y*wd);
        }
        *(uint4*)(outh + (size_t)node*FEAT + fl*8) = pk.u;
    }
}

__global__ void k_goff(const int* __restrict__ gid, int* __restrict__ goff){
    int g = blockIdx.x*blockDim.x + threadIdx.x;
    if (g > N_GRAPHS) return;
    if (g == N_GRAPHS){ goff[g] = N_NODES; return; }
    int lo = 0, hi = N_NODES;
    while (lo < hi){
        int mid = (lo + hi) >> 1;
        if (gid[mid] < g) lo = mid + 1; else hi = mid;
    }
    goff[g] = lo;
}

// readout on fp16 aggregate: 4 chunk-blocks per graph, 16 rows x 16 uint4 lanes
__global__ __launch_bounds__(256) void k_readout_h(
        const __half* __restrict__ ah, const int* __restrict__ goff,
        float* __restrict__ emb_part){
    __shared__ float red[16][FEAT];
    int g = blockIdx.x >> 2, c = blockIdx.x & 3;
    int t = threadIdx.x;
    int fl = t & 15, rs = t >> 4;
    int beg = goff[g], end = goff[g+1];
    int cnt = end - beg;
    int chunk = (cnt + 3) >> 2;
    int lo = beg + c*chunk;
    int hi = lo + chunk; if (hi > end) hi = end;
    float acc[8] = {0,0,0,0,0,0,0,0};
    for (int r = lo + rs; r < hi; r += 16){
        uint4 v = *(const uint4*)(ah + (size_t)r*FEAT + fl*8);
        const __half2* h = (const __half2*)&v;
        #pragma unroll
        for (int q = 0; q < 4; ++q){
            float2 f = __half22float2(h[q]);
            acc[2*q]   += f.x;
            acc[2*q+1] += f.y;
        }
    }
    #pragma unroll
    for (int q = 0; q < 8; ++q) red[rs][fl*8+q] = acc[q];
    __syncthreads();
    if (t < FEAT){
        float s = 0.f;
        #pragma unroll
        for (int i = 0; i < 16; ++i) s += red[i][t];
        emb_part[((size_t)g*4 + c)*FEAT + t] = s;
    }
}

// block per graph: mean(parts) -> @W3+b3 -> concat fg -> 136->256->128->1 MLP
__global__ __launch_bounds__(256) void k_mlp(
        const float* __restrict__ emb_part, const int* __restrict__ goff,
        const float* __restrict__ fg,
        const float* __restrict__ W3, const float* __restrict__ b3,
        const float* __restrict__ Wl1, const float* __restrict__ bl1,
        const float* __restrict__ Wl2, const float* __restrict__ bl2,
        const float* __restrict__ Wl3, const float* __restrict__ bl3,
        float* __restrict__ out){
    __shared__ float e[FEAT];
    __shared__ float in136[FEAT+EXTRA];
    __shared__ float y1[256];
    __shared__ float y2[128];
    int g = blockIdx.x, t = threadIdx.x;
    int cnt = goff[g+1] - goff[g]; if (cnt < 1) cnt = 1;
    float inv = 1.f / (float)cnt;
    if (t < FEAT){
        const float* p = emb_part + (size_t)g*4*FEAT;
        e[t] = (p[t] + p[FEAT+t] + p[2*FEAT+t] + p[3*FEAT+t]) * inv;
    }
    __syncthreads();
    if (t < FEAT){
        float acc = b3[t];
        for (int i = 0; i < FEAT; ++i) acc += e[i] * W3[i*FEAT + t];
        in136[t] = acc;
    } else if (t < FEAT+EXTRA){
        in136[t] = fg[g*EXTRA + (t-FEAT)];
    }
    __syncthreads();
    {
        float acc = bl1[t];
        for (int i = 0; i < FEAT+EXTRA; ++i) acc += in136[i] * Wl1[i*256 + t];
        y1[t] = selu_f(acc);
    }
    __syncthreads();
    if (t < 128){
        float acc = bl2[t];
        for (int i = 0; i < 256; ++i) acc += y1[i] * Wl2[i*128 + t];
        y2[t] = selu_f(acc);
    }
    __syncthreads();
    if (t == 0){
        float s = bl3[0];
        for (int i = 0; i < 128; ++i) s += y2[i] * Wl3[i];
        out[g] = s;
    }
}

extern "C" void kernel_launch(void* const* d_in, const int* in_sizes, int n_in,
                              void* d_out, int out_size, void* d_ws, size_t ws_size,
                              hipStream_t stream){
    const float* feats_node  = (const float*)d_in[0];
    const float* feats_graph = (const float*)d_in[1];
    const int*   edge_src    = (const int*)d_in[2];
    const int*   edge_dst    = (const int*)d_in[3];
    const int*   graph_ids   = (const int*)d_in[4];
    const float* W1 =(const float*)d_in[5];  const float* b1 =(const float*)d_in[6];
    const float* W2 =(const float*)d_in[7];  const float* b2 =(const float*)d_in[8];
    const float* W3 =(const float*)d_in[9];  const float* b3 =(const float*)d_in[10];
    const float* Wl1=(const float*)d_in[11]; const float* bl1=(const float*)d_in[12];
    const float* Wl2=(const float*)d_in[13]; const float* bl2=(const float*)d_in[14];
    const float* Wl3=(const float*)d_in[15]; const float* bl3=(const float*)d_in[16];
    float* out = (float*)d_out;
    (void)in_sizes; (void)n_in; (void)out_size; (void)ws_size;

    char* ws = (char*)d_ws;
    size_t off = 0;
    auto alloc = [&](size_t bytes)->void*{
        void* p = ws + off;
        off += (bytes + 255) & ~(size_t)255;
        return p;
    };
    __half*   xhA     = (__half*)  alloc((size_t)N_NODES*FEAT*2);
    __half*   xhB     = (__half*)  alloc((size_t)N_NODES*FEAT*2);
    __half*   ah      = (__half*)  alloc((size_t)N_NODES*FEAT*2);
    float*    ns      = (float*)   alloc((size_t)N_NODES*4);
    float*    nd      = (float*)   alloc((size_t)N_NODES*4);
    int*      row_beg = (int*)     alloc((size_t)N_NODES*4);
    int*      row_end = (int*)     alloc((size_t)N_NODES*4);
    int*      col     = (int*)     alloc((size_t)NB*CAPB*4);
    unsigned* tmp     = (unsigned*)alloc((size_t)NB*CAPB*4);
    ushort*   tmp2    = (ushort*)  alloc((size_t)NB*CAPB*2);
    int*      gcursor = (int*)     alloc((size_t)NB*4);
    int*      scursor = (int*)     alloc((size_t)NB*4);
    __half*   Wf1     = (__half*)  alloc((size_t)16384*2);
    __half*   Wf2     = (__half*)  alloc((size_t)16384*2);
    int*      goff    = (int*)     alloc((size_t)(N_GRAPHS+1)*4);
    float*    emb_part= (float*)   alloc((size_t)N_GRAPHS*4*FEAT*4);

    // strided-bucket CSR build (no histogram, no serial scan; packed payload)
    k_initcur<<<dim3(1), dim3(256), 0, stream>>>(gcursor, scursor);
    k_passA2<<<dim3((N_EDGES + PA_T - 1)/PA_T), dim3(256), 0, stream>>>(
        edge_src, edge_dst, gcursor, scursor, tmp, tmp2);
    k_passB<<<dim3(NB), dim3(256), 0, stream>>>(tmp, gcursor, row_beg, row_end, col, nd);
    k_srchist<<<dim3(NB), dim3(256), 0, stream>>>(tmp2, scursor, ns);

    // weight fragment swizzle (fp16)
    k_wprep2<<<dim3(128), dim3(256), 0, stream>>>(W1, Wf1, W2, Wf2);

    // fp16 pre-scaled input
    k_prep<<<dim3((N_NODES*64 + 255)/256), dim3(256), 0, stream>>>(
        (const float2*)feats_node, ns, (__half2*)xhA);

    // graph offsets
    k_goff<<<dim3((N_GRAPHS+1+255)/256), dim3(256), 0, stream>>>(graph_ids, goff);

    // layers 1,2 fused (agg+GEMM, one wave per node); layer 3 aggregate only
    dim3 fusedGrid(N_NODES/16);                // 6250, exact
    dim3 aggGrid((N_NODES*64 + 255)/256);
    k_agg_gemm<<<fusedGrid, dim3(1024), 0, stream>>>(
        xhA, row_beg, row_end, col, nd, Wf1, b1, ns, xhB);
    k_agg_gemm<<<fusedGrid, dim3(1024), 0, stream>>>(
        xhB, row_beg, row_end, col, nd, Wf2, b2, ns, xhA);
    k_aggregate_h<<<aggGrid, dim3(256), 0, stream>>>(xhA, row_beg, row_end, col, nd, ah);

    // readout + fused (mean @ W3 + b3) inside MLP
    k_readout_h<<<dim3(N_GRAPHS*4), dim3(256), 0, stream>>>(ah, goff, emb_part);
    k_mlp<<<dim3(N_GRAPHS), dim3(256), 0, stream>>>(emb_part, goff, feats_graph,
        W3, b3, Wl1, bl1, Wl2, bl2, Wl3, bl3, out);
}